// Round 4
// baseline (277.470 us; speedup 1.0000x reference)
//
#include <hip/hip_runtime.h>
#include <hip/hip_bf16.h>

typedef __bf16 bf16x8 __attribute__((ext_vector_type(8)));
typedef __bf16 bf16x4 __attribute__((ext_vector_type(4)));
typedef __bf16 bf16x2 __attribute__((ext_vector_type(2)));
typedef float  f32x4  __attribute__((ext_vector_type(4)));

#define T_SEQ 2048
#define D_HEAD 64
#define BH_N 32
#define TK 64
#define G_SPLIT 4
#define SCALE_LOG2 0.18033688011112042f   // 0.125 * log2(e)

// workspace layout (bytes)
#define WS_KBF ((size_t)0)
#define WS_VTB ((size_t)8u<<20)
#define WS_QB  ((size_t)16u<<20)
#define WS_MB  ((size_t)24u<<20)
#define WS_OG  (((size_t)24u<<20) + (512u<<10))
#define WS_LG  (WS_OG + (size_t)G_SPLIT*BH_N*T_SEQ*D_HEAD*2)   // og = 32 MiB
#define WS_NEED_G4 (WS_LG + (size_t)G_SPLIT*BH_N*T_SEQ*4)
#define WS_NEED_R2 (((size_t)16u<<20) + (size_t)T_SEQ*32*8)

// ---------------- pre-pass kernels ----------------

__global__ void cvt_k(const float* __restrict__ k, __bf16* __restrict__ kb) {
    const int i = (blockIdx.x * 256 + threadIdx.x) * 8;
    const float4 a = *(const float4*)(k + i);
    const float4 b = *(const float4*)(k + i + 4);
    bf16x8 w;
    w[0]=(__bf16)a.x; w[1]=(__bf16)a.y; w[2]=(__bf16)a.z; w[3]=(__bf16)a.w;
    w[4]=(__bf16)b.x; w[5]=(__bf16)b.y; w[6]=(__bf16)b.z; w[7]=(__bf16)b.w;
    *(bf16x8*)(kb + i) = w;
}

__global__ void cvt_q(const float* __restrict__ q, __bf16* __restrict__ qb) {
    const int i = (blockIdx.x * 256 + threadIdx.x) * 8;
    const float4 a = *(const float4*)(q + i);
    const float4 b = *(const float4*)(q + i + 4);
    bf16x8 w;
    w[0]=(__bf16)(a.x*SCALE_LOG2); w[1]=(__bf16)(a.y*SCALE_LOG2);
    w[2]=(__bf16)(a.z*SCALE_LOG2); w[3]=(__bf16)(a.w*SCALE_LOG2);
    w[4]=(__bf16)(b.x*SCALE_LOG2); w[5]=(__bf16)(b.y*SCALE_LOG2);
    w[6]=(__bf16)(b.z*SCALE_LOG2); w[7]=(__bf16)(b.w*SCALE_LOG2);
    *(bf16x8*)(qb + i) = w;
}

__global__ void vtrans(const float* __restrict__ v, __bf16* __restrict__ vt) {
    __shared__ __bf16 t[64][72];
    const int bh = blockIdx.y, tt = blockIdx.x, tid = threadIdx.x;
    const int tr = tid >> 4, c4 = (tid & 15) * 4;
    const float* src = v + ((size_t)bh * T_SEQ + tt * 64) * D_HEAD;
#pragma unroll
    for (int p = 0; p < 4; ++p) {
        const int row = p * 16 + tr;
        const float4 f = *(const float4*)(src + row * D_HEAD + c4);
        t[c4+0][row] = (__bf16)f.x; t[c4+1][row] = (__bf16)f.y;
        t[c4+2][row] = (__bf16)f.z; t[c4+3][row] = (__bf16)f.w;
    }
    __syncthreads();
    const int d = tid >> 2, seg = tid & 3;
    const bf16x8 a = *(bf16x8*)&t[d][seg*16];
    const bf16x8 b = *(bf16x8*)&t[d][seg*16+8];
    __bf16* dst = vt + ((size_t)bh * D_HEAD + d) * T_SEQ + tt * 64 + seg * 16;
    *(bf16x8*)dst = a; *(bf16x8*)(dst + 8) = b;
}

__global__ void mpack(const int* __restrict__ m, unsigned long long* __restrict__ mb) {
    const int i = blockIdx.x * 256 + threadIdx.x;
    const unsigned long long b = __ballot(m[i] != 0);
    if ((threadIdx.x & 63) == 0) mb[i >> 6] = b;
}

// ---------------- main kernel: 64 q-rows/wave, K-split G=4, XCD-swizzled ----------------
// S^T formulation (A=K frag, B=Q frag). No running max (log2-domain, fp32-safe).
// Partial unnormalized O (bf16, coalesced via LDS) + partial l -> reduce kernel.

__global__ __launch_bounds__(256, 3) void attn_g4(
    const __bf16* __restrict__ qb, const __bf16* __restrict__ kb,
    const __bf16* __restrict__ vt, const unsigned long long* __restrict__ mb,
    __bf16* __restrict__ og, float* __restrict__ lg)
{
    // XCD-aware decode: xcd = l&7 (dispatch round-robin heuristic).
    // slice = xcd + 8*(l>>6) -> all 8 qt-blocks of a (gi,bh) slice on one XCD;
    // gi in slice high bits -> all 4 gi-blocks of a (qt,bh) Q tile also same XCD.
    const int l = blockIdx.x;            // 0..1023
    const int t = l >> 3;                // 0..127
    const int qt = t & 7;                // 0..7
    const int slice = (l & 7) + 8 * (t >> 3);   // 0..127
    const int bh = slice & 31;
    const int gi = slice >> 5;           // 0..3

    const int tid = threadIdx.x, wave = tid >> 6, lane = tid & 63;
    const int g = lane >> 4, ln = lane & 15;

    __shared__ __align__(16) __bf16 Kl[TK * 64];       // swizzled, stride 128B
    __shared__ __align__(16) __bf16 Vl[D_HEAD * 64];   // swizzled, stride 128B
    __shared__ __align__(16) __bf16 Pl[4][64 * 72];    // per-wave P [qrow][key], padded

    const int qw = qt * 256 + wave * 64;

    // Q B-frags from bf16 (scale pre-folded): lane n=ln holds Q[q=qs*16+ln][d=kc*32+g*8+j]
    bf16x8 qf[4][2];
#pragma unroll
    for (int qs = 0; qs < 4; ++qs) {
        const __bf16* qp = qb + ((size_t)bh * T_SEQ + qw + qs*16 + ln) * D_HEAD + g * 8;
        qf[qs][0] = *(const bf16x8*)(qp);
        qf[qs][1] = *(const bf16x8*)(qp + 32);
    }

    f32x4 o[4][4];
#pragma unroll
    for (int qs = 0; qs < 4; ++qs)
#pragma unroll
        for (int mt = 0; mt < 4; ++mt) o[qs][mt] = (f32x4){0.f,0.f,0.f,0.f};
    float lsum[4] = {0.f, 0.f, 0.f, 0.f};

    // LDS frag read base (bytes): row=ln (stride 128B), chunk g ^ (ln&7)
    const int rb = ln * 128 + ((g ^ (ln & 7)) * 16);
    // staging: thread -> row kr, 32B at col seg*16; chunks swizzled by row&7
    const int kr = tid >> 2, seg = tid & 3;
    const int sw = kr * 128 + (((2*seg) ^ (kr & 7)) * 16);
    const __bf16* kbase = kb + (size_t)bh * T_SEQ * D_HEAD;
    const __bf16* vbase = vt + (size_t)bh * D_HEAD * T_SEQ;
    const unsigned long long* mbase = mb + (size_t)(qw + ln) * 32;

    char* KlB = (char*)Kl;
    char* VlB = (char*)Vl;

    const int kt0 = gi * (T_SEQ / TK / G_SPLIT);
    for (int ki = 0; ki < T_SEQ / TK / G_SPLIT; ++ki) {
        const int kt = kt0 + ki;
        unsigned long long mw[4];
#pragma unroll
        for (int qs = 0; qs < 4; ++qs) mw[qs] = mbase[qs * 16 * 32 + kt];

        __syncthreads();
        {
            const __bf16* kp = kbase + (size_t)(kt * TK + kr) * D_HEAD + seg * 16;
            const bf16x8 k0 = *(const bf16x8*)kp;
            const bf16x8 k1 = *(const bf16x8*)(kp + 8);
            *(bf16x8*)(KlB + sw)        = k0;
            *(bf16x8*)(KlB + (sw ^ 16)) = k1;
            const __bf16* vp = vbase + (size_t)kr * T_SEQ + kt * TK + seg * 16;
            const bf16x8 v0 = *(const bf16x8*)vp;
            const bf16x8 v1 = *(const bf16x8*)(vp + 8);
            *(bf16x8*)(VlB + sw)        = v0;
            *(bf16x8*)(VlB + (sw ^ 16)) = v1;
        }
        __syncthreads();

        unsigned int mlo[4], mhi[4];
#pragma unroll
        for (int qs = 0; qs < 4; ++qs) {
            const unsigned long long wsh = mw[qs] >> (g * 4);
            mlo[qs] = (unsigned)wsh; mhi[qs] = (unsigned)(wsh >> 32);
        }

        // ---- S^T = K . Q^T, exp2, mask, P write (packed b64)
#pragma unroll
        for (int nt = 0; nt < 4; ++nt) {
            const bf16x8 a0 = *(const bf16x8*)(KlB + nt * 2048 + rb);
            const bf16x8 a1 = *(const bf16x8*)(KlB + nt * 2048 + (rb ^ 64));
#pragma unroll
            for (int qs = 0; qs < 4; ++qs) {
                f32x4 c = (f32x4){0.f,0.f,0.f,0.f};
                c = __builtin_amdgcn_mfma_f32_16x16x32_bf16(a0, qf[qs][0], c, 0,0,0);
                c = __builtin_amdgcn_mfma_f32_16x16x32_bf16(a1, qf[qs][1], c, 0,0,0);
                const unsigned int bits = (nt < 2) ? mlo[qs] : mhi[qs];
                float p[4];
#pragma unroll
                for (int r = 0; r < 4; ++r) {
                    const float e = exp2f(c[r]);
                    p[r] = (bits & (1u << ((nt & 1) * 16 + r))) ? 0.f : e;
                }
                lsum[qs] += (p[0] + p[1]) + (p[2] + p[3]);
                bf16x4 pk = { (__bf16)p[0], (__bf16)p[1], (__bf16)p[2], (__bf16)p[3] };
                *(bf16x4*)(&Pl[wave][(qs*16 + ln) * 72 + nt * 16 + g * 4]) = pk;
            }
        }

        // ---- PV: A = V^T (LDS), B = P^T (= P[q=ln][key] rows, b128)
        bf16x8 pf[4][2];
#pragma unroll
        for (int qs = 0; qs < 4; ++qs)
#pragma unroll
            for (int kc = 0; kc < 2; ++kc)
                pf[qs][kc] = *(const bf16x8*)(&Pl[wave][(qs*16 + ln) * 72 + kc * 32 + g * 8]);
#pragma unroll
        for (int mt = 0; mt < 4; ++mt) {
            const bf16x8 a0 = *(const bf16x8*)(VlB + mt * 2048 + rb);
            const bf16x8 a1 = *(const bf16x8*)(VlB + mt * 2048 + (rb ^ 64));
#pragma unroll
            for (int qs = 0; qs < 4; ++qs) {
                o[qs][mt] = __builtin_amdgcn_mfma_f32_16x16x32_bf16(a0, pf[qs][0], o[qs][mt], 0,0,0);
                o[qs][mt] = __builtin_amdgcn_mfma_f32_16x16x32_bf16(a1, pf[qs][1], o[qs][mt], 0,0,0);
            }
        }
    }

    // ---- epilogue: dump O^T frags into Pl row-major [q][d] (stride 72), then
    //      coalesced og stores (each thread 16B chunks; waves write 1KB lines)
#pragma unroll
    for (int qs = 0; qs < 4; ++qs) {
#pragma unroll
        for (int mt = 0; mt < 4; ++mt) {
            const f32x4 vv = o[qs][mt];
            bf16x4 pk = { (__bf16)vv[0], (__bf16)vv[1], (__bf16)vv[2], (__bf16)vv[3] };
            *(bf16x4*)(&Pl[wave][(qs*16 + ln) * 72 + mt * 16 + g * 4]) = pk;
        }
        float lr = lsum[qs];
        lr += __shfl_xor(lr, 16, 64);
        lr += __shfl_xor(lr, 32, 64);
        if (g == 0)
            lg[(size_t)(gi * BH_N + bh) * T_SEQ + qw + qs*16 + ln] = lr;
    }
    __syncthreads();
    __bf16* ob = og + ((size_t)(gi * BH_N + bh) * T_SEQ + qt * 256) * D_HEAD;
#pragma unroll
    for (int j = 0; j < 8; ++j) {
        const int flat = tid * 16 + j * 4096;   // byte offset in block's 32KB og tile
        const int row = flat >> 7;              // 0..255
        const int col = flat & 127;             // byte col within 128B row
        const bf16x8 val = *(const bf16x8*)(&Pl[row >> 6][(row & 63) * 72 + (col >> 1)]);
        *(bf16x8*)((char*)ob + flat) = val;
    }
}

// ---------------- reduce: out = (sum_g Og) / (sum_g lg) ----------------

__global__ void reduce_o(const __bf16* __restrict__ og, const float* __restrict__ lg,
                         float* __restrict__ out)
{
    const int t = blockIdx.x * 256 + threadIdx.x;   // BH_N*T_SEQ*16 threads
    const int row = t >> 4;                         // bh*T_SEQ + q
    const int d4 = (t & 15) * 4;
    float l = 0.f;
#pragma unroll
    for (int gi = 0; gi < G_SPLIT; ++gi) l += lg[(size_t)gi * BH_N * T_SEQ + row];
    const float inv = (l > 0.f) ? (1.f / l) : 0.f;
    float acc[4] = {0.f, 0.f, 0.f, 0.f};
#pragma unroll
    for (int gi = 0; gi < G_SPLIT; ++gi) {
        const bf16x4 p = *(const bf16x4*)(og + ((size_t)gi * BH_N * T_SEQ + row) * D_HEAD + d4);
        acc[0] += (float)p[0]; acc[1] += (float)p[1];
        acc[2] += (float)p[2]; acc[3] += (float)p[3];
    }
    const float4 st = { acc[0]*inv, acc[1]*inv, acc[2]*inv, acc[3]*inv };
    *(float4*)(out + (size_t)row * D_HEAD + d4) = st;
}

// ---------------- round-2 single-pass path (fallback if ws < WS_NEED_G4) ----------------

__global__ __launch_bounds__(256) void attn_r2(
    const float* __restrict__ q, const __bf16* __restrict__ kb,
    const __bf16* __restrict__ vt, const unsigned long long* __restrict__ mb,
    float* __restrict__ out)
{
    const int qt = blockIdx.x, bh = blockIdx.y;
    const int tid = threadIdx.x, wave = tid >> 6, lane = tid & 63;
    const int g = lane >> 4, ln = lane & 15;
    __shared__ __align__(16) __bf16 Kl[TK * 64];
    __shared__ __align__(16) __bf16 Vl[D_HEAD * 64];
    __shared__ __align__(16) __bf16 Pl[4][32 * 72];
    const int qw = qt * 128 + wave * 32;
    bf16x8 qf[2][2];
#pragma unroll
    for (int qs = 0; qs < 2; ++qs) {
        const float* qp = q + ((size_t)bh * T_SEQ + qw + qs*16 + ln) * D_HEAD + g * 8;
#pragma unroll
        for (int kc = 0; kc < 2; ++kc) {
            const float4 f0 = *(const float4*)(qp + kc * 32);
            const float4 f1 = *(const float4*)(qp + kc * 32 + 4);
            qf[qs][kc][0]=(__bf16)(f0.x*SCALE_LOG2); qf[qs][kc][1]=(__bf16)(f0.y*SCALE_LOG2);
            qf[qs][kc][2]=(__bf16)(f0.z*SCALE_LOG2); qf[qs][kc][3]=(__bf16)(f0.w*SCALE_LOG2);
            qf[qs][kc][4]=(__bf16)(f1.x*SCALE_LOG2); qf[qs][kc][5]=(__bf16)(f1.y*SCALE_LOG2);
            qf[qs][kc][6]=(__bf16)(f1.z*SCALE_LOG2); qf[qs][kc][7]=(__bf16)(f1.w*SCALE_LOG2);
        }
    }
    f32x4 o[2][4];
#pragma unroll
    for (int qs = 0; qs < 2; ++qs)
#pragma unroll
        for (int mt = 0; mt < 4; ++mt) o[qs][mt] = (f32x4){0.f,0.f,0.f,0.f};
    float lsum[2] = {0.f, 0.f};
    const int rb = ln * 128 + ((g ^ (ln & 7)) * 16);
    const int kr = tid >> 2, seg = tid & 3;
    const int sw = kr * 128 + (((2*seg) ^ (kr & 7)) * 16);
    const __bf16* kbase = kb + (size_t)bh * T_SEQ * D_HEAD;
    const __bf16* vbase = vt + (size_t)bh * D_HEAD * T_SEQ;
    const unsigned long long* mrow0 = mb + (size_t)(qw + ln) * 32;
    const unsigned long long* mrow1 = mb + (size_t)(qw + 16 + ln) * 32;
    char* KlB = (char*)Kl; char* VlB = (char*)Vl;
    for (int kt = 0; kt < T_SEQ / TK; ++kt) {
        const unsigned long long w0 = mrow0[kt], w1 = mrow1[kt];
        __syncthreads();
        {
            const __bf16* kp = kbase + (size_t)(kt * TK + kr) * D_HEAD + seg * 16;
            const bf16x8 k0 = *(const bf16x8*)kp;
            const bf16x8 k1 = *(const bf16x8*)(kp + 8);
            *(bf16x8*)(KlB + sw)        = k0;
            *(bf16x8*)(KlB + (sw ^ 16)) = k1;
            const __bf16* vp = vbase + (size_t)kr * T_SEQ + kt * TK + seg * 16;
            const bf16x8 v0 = *(const bf16x8*)vp;
            const bf16x8 v1 = *(const bf16x8*)(vp + 8);
            *(bf16x8*)(VlB + sw)        = v0;
            *(bf16x8*)(VlB + (sw ^ 16)) = v1;
        }
        __syncthreads();
        const unsigned long long ws0 = w0 >> (g * 4), ws1 = w1 >> (g * 4);
        const unsigned int mlo[2] = {(unsigned)ws0, (unsigned)ws1};
        const unsigned int mhi[2] = {(unsigned)(ws0 >> 32), (unsigned)(ws1 >> 32)};
#pragma unroll
        for (int nt = 0; nt < 4; ++nt) {
            const bf16x8 a0 = *(const bf16x8*)(KlB + nt * 2048 + rb);
            const bf16x8 a1 = *(const bf16x8*)(KlB + nt * 2048 + (rb ^ 64));
#pragma unroll
            for (int qs = 0; qs < 2; ++qs) {
                f32x4 c = (f32x4){0.f,0.f,0.f,0.f};
                c = __builtin_amdgcn_mfma_f32_16x16x32_bf16(a0, qf[qs][0], c, 0,0,0);
                c = __builtin_amdgcn_mfma_f32_16x16x32_bf16(a1, qf[qs][1], c, 0,0,0);
                const unsigned int bits = (nt < 2) ? mlo[qs] : mhi[qs];
                float p[4];
#pragma unroll
                for (int r = 0; r < 4; ++r) {
                    const float e = exp2f(c[r]);
                    p[r] = (bits & (1u << ((nt & 1) * 16 + r))) ? 0.f : e;
                }
                lsum[qs] += (p[0] + p[1]) + (p[2] + p[3]);
                bf16x4 pk = { (__bf16)p[0], (__bf16)p[1], (__bf16)p[2], (__bf16)p[3] };
                *(bf16x4*)(&Pl[wave][(qs*16 + ln) * 72 + nt * 16 + g * 4]) = pk;
            }
        }
        bf16x8 pf[2][2];
#pragma unroll
        for (int qs = 0; qs < 2; ++qs)
#pragma unroll
            for (int kc = 0; kc < 2; ++kc)
                pf[qs][kc] = *(const bf16x8*)(&Pl[wave][(qs*16 + ln) * 72 + kc * 32 + g * 8]);
#pragma unroll
        for (int mt = 0; mt < 4; ++mt) {
            const bf16x8 a0 = *(const bf16x8*)(VlB + mt * 2048 + rb);
            const bf16x8 a1 = *(const bf16x8*)(VlB + mt * 2048 + (rb ^ 64));
#pragma unroll
            for (int qs = 0; qs < 2; ++qs) {
                o[qs][mt] = __builtin_amdgcn_mfma_f32_16x16x32_bf16(a0, pf[qs][0], o[qs][mt], 0,0,0);
                o[qs][mt] = __builtin_amdgcn_mfma_f32_16x16x32_bf16(a1, pf[qs][1], o[qs][mt], 0,0,0);
            }
        }
    }
#pragma unroll
    for (int qs = 0; qs < 2; ++qs) {
        float l = lsum[qs];
        l += __shfl_xor(l, 16, 64);
        l += __shfl_xor(l, 32, 64);
        const float inv = (l > 0.f) ? (1.f / l) : 0.f;
        float* op = out + ((size_t)bh * T_SEQ + qw + qs*16 + ln) * D_HEAD + g * 4;
#pragma unroll
        for (int mt = 0; mt < 4; ++mt) {
            const f32x4 vv = o[qs][mt];
            const float4 st = {vv[0]*inv, vv[1]*inv, vv[2]*inv, vv[3]*inv};
            *(float4*)(op + mt * 16) = st;
        }
    }
}

extern "C" void kernel_launch(void* const* d_in, const int* in_sizes, int n_in,
                              void* d_out, int out_size, void* d_ws, size_t ws_size,
                              hipStream_t stream) {
    const float* q    = (const float*)d_in[0];
    const float* k    = (const float*)d_in[1];
    const float* v    = (const float*)d_in[2];
    const int*   mask = (const int*)d_in[3];
    float*       out  = (float*)d_out;

    if (ws_size >= WS_NEED_R2) {
        __bf16* kbf = (__bf16*)((char*)d_ws + WS_KBF);
        __bf16* vtb = (__bf16*)((char*)d_ws + WS_VTB);
        cvt_k<<<(BH_N * T_SEQ * D_HEAD) / (256 * 8), 256, 0, stream>>>(k, kbf);
        vtrans<<<dim3(T_SEQ / 64, BH_N), 256, 0, stream>>>(v, vtb);
        if (ws_size >= WS_NEED_G4) {
            __bf16* qbf = (__bf16*)((char*)d_ws + WS_QB);
            unsigned long long* mbw = (unsigned long long*)((char*)d_ws + WS_MB);
            __bf16* og = (__bf16*)((char*)d_ws + WS_OG);
            float*  lg = (float*)((char*)d_ws + WS_LG);
            cvt_q<<<(BH_N * T_SEQ * D_HEAD) / (256 * 8), 256, 0, stream>>>(q, qbf);
            mpack<<<(T_SEQ * T_SEQ) / 256, 256, 0, stream>>>(mask, mbw);
            attn_g4<<<G_SPLIT * (T_SEQ / 256) * BH_N, 256, 0, stream>>>(qbf, kbf, vtb, mbw, og, lg);
            reduce_o<<<(BH_N * T_SEQ * 16) / 256, 256, 0, stream>>>(og, lg, out);
        } else {
            unsigned long long* mbw = (unsigned long long*)((char*)d_ws + (16u<<20));
            mpack<<<(T_SEQ * T_SEQ) / 256, 256, 0, stream>>>(mask, mbw);
            attn_r2<<<dim3(T_SEQ / 128, BH_N), 256, 0, stream>>>(q, kbf, vtb, mbw, out);
        }
    } else {
        // guard: ws has always been >= WS_NEED_R2 in practice
        attn_r2<<<dim3(T_SEQ / 128, BH_N), 256, 0, stream>>>(q, (const __bf16*)d_ws,
                                                             (const __bf16*)d_ws,
                                                             (const unsigned long long*)d_ws, out);
    }
}

// Round 5
// 185.740 us; speedup vs baseline: 1.4939x; 1.4939x over previous
//
#include <hip/hip_runtime.h>
#include <hip/hip_bf16.h>

typedef __bf16 bf16x8 __attribute__((ext_vector_type(8)));
typedef __bf16 bf16x4 __attribute__((ext_vector_type(4)));
typedef float  f32x4  __attribute__((ext_vector_type(4)));
typedef short  s16x4  __attribute__((ext_vector_type(4)));

#define T_SEQ 2048
#define D_HEAD 64
#define BH_N 32
#define SCALE_LOG2 0.18033688011112042f   // 0.125 * log2(e)

// workspace layout (bytes); kbf 8MB, vtb 8MB, mask bitwords 512KB
#define WS_KBF ((size_t)0)
#define WS_VTB ((size_t)8u<<20)
#define WS_MB  ((size_t)16u<<20)

// D = A*B + C, 16x16x16 bf16 (K=16). A: [m=lane&15][k=(lane>>4)*4+r]
static __device__ inline f32x4 mfma16(bf16x4 a, bf16x4 b, f32x4 c) {
#if __has_builtin(__builtin_amdgcn_mfma_f32_16x16x16_bf16)
    return __builtin_amdgcn_mfma_f32_16x16x16_bf16(a, b, c, 0, 0, 0);
#else
    s16x4 ai = __builtin_bit_cast(s16x4, a);
    s16x4 bi = __builtin_bit_cast(s16x4, b);
    return __builtin_amdgcn_mfma_f32_16x16x16bf16_1k(ai, bi, c, 0, 0, 0);
#endif
}

// ---------------- fused prepass: K -> bf16 [bh][t][d], V -> bf16 transposed [bh][d][t] ----------------

__global__ __launch_bounds__(256) void prep_kv(const float* __restrict__ k,
                                               const float* __restrict__ v,
                                               __bf16* __restrict__ kb,
                                               __bf16* __restrict__ vt) {
    __shared__ __bf16 t[64][72];
    const int bh = blockIdx.y, tt = blockIdx.x, tid = threadIdx.x;

    // ---- K convert: row tid>>2, 16 floats at (tid&3)*16
    {
        const size_t base = ((size_t)bh * T_SEQ + tt * 64 + (tid >> 2)) * D_HEAD + (tid & 3) * 16;
        const float4 a0 = *(const float4*)(k + base);
        const float4 a1 = *(const float4*)(k + base + 4);
        const float4 a2 = *(const float4*)(k + base + 8);
        const float4 a3 = *(const float4*)(k + base + 12);
        bf16x8 w0, w1;
        w0[0]=(__bf16)a0.x; w0[1]=(__bf16)a0.y; w0[2]=(__bf16)a0.z; w0[3]=(__bf16)a0.w;
        w0[4]=(__bf16)a1.x; w0[5]=(__bf16)a1.y; w0[6]=(__bf16)a1.z; w0[7]=(__bf16)a1.w;
        w1[0]=(__bf16)a2.x; w1[1]=(__bf16)a2.y; w1[2]=(__bf16)a2.z; w1[3]=(__bf16)a2.w;
        w1[4]=(__bf16)a3.x; w1[5]=(__bf16)a3.y; w1[6]=(__bf16)a3.z; w1[7]=(__bf16)a3.w;
        *(bf16x8*)(kb + base)     = w0;
        *(bf16x8*)(kb + base + 8) = w1;
    }
    // ---- V transpose via LDS
    {
        const int tr = tid >> 4, c4 = (tid & 15) * 4;
        const float* src = v + ((size_t)bh * T_SEQ + tt * 64) * D_HEAD;
#pragma unroll
        for (int p = 0; p < 4; ++p) {
            const int row = p * 16 + tr;
            const float4 f = *(const float4*)(src + row * D_HEAD + c4);
            t[c4+0][row] = (__bf16)f.x; t[c4+1][row] = (__bf16)f.y;
            t[c4+2][row] = (__bf16)f.z; t[c4+3][row] = (__bf16)f.w;
        }
        __syncthreads();
        const int d = tid >> 2, seg = tid & 3;
        const bf16x8 a = *(bf16x8*)&t[d][seg * 16];
        const bf16x8 b = *(bf16x8*)&t[d][seg * 16 + 8];
        __bf16* dst = vt + ((size_t)bh * D_HEAD + d) * T_SEQ + tt * 64 + seg * 16;
        *(bf16x8*)dst = a; *(bf16x8*)(dst + 8) = b;
    }
}

__global__ void mpack(const int* __restrict__ m, unsigned long long* __restrict__ mb) {
    const int i = blockIdx.x * 256 + threadIdx.x;
    const unsigned long long b = __ballot(m[i] != 0);
    if ((threadIdx.x & 63) == 0) mb[i >> 6] = b;
}

// ---------------- main kernel ----------------
// S^T = K.Q^T via 16x16x32 MFMA (A=K from LDS, B=Q regs). P stays in REGISTERS:
// the S^T C-layout is exactly the A-layout of 16x16x16 MFMA, so PV = mfma16(P, V-frag)
// giving O[q][d] directly. K/V double-buffered in LDS with register prefetch.
// No running max (log2-domain scores bounded; fp32 exp2 safe). Mask via u64 bitwords.

__global__ __launch_bounds__(128, 2) void attn5(
    const float* __restrict__ q, const __bf16* __restrict__ kb,
    const __bf16* __restrict__ vt, const unsigned long long* __restrict__ mb,
    float* __restrict__ out)
{
    const int qt = blockIdx.x;   // 0..31 (fast dim -> same-bh blocks adjacent in dispatch)
    const int bh = blockIdx.y;   // 0..31
    const int tid = threadIdx.x, wave = tid >> 6, lane = tid & 63;
    const int g = lane >> 4, ln = lane & 15;

    __shared__ __align__(16) __bf16 Kl[2][64 * 64];   // [key][d], 16B-XOR swizzle, stride 128B
    __shared__ __align__(16) __bf16 Vl[2][64 * 64];   // [d][key], 8B-XOR swizzle, stride 128B
    __shared__ float ls[2][32];                       // per-wave 1/l

    const int qw = qt * 64 + wave * 32;

    // ---- Q B-frags (log2-scaled): lane n=ln holds Q[q=qw+qs*16+ln][d=kc*32+g*8+j]
    bf16x8 qf[2][2];
#pragma unroll
    for (int qs = 0; qs < 2; ++qs) {
        const float* qp = q + ((size_t)bh * T_SEQ + qw + qs * 16 + ln) * D_HEAD + g * 8;
#pragma unroll
        for (int kc = 0; kc < 2; ++kc) {
            const float4 f0 = *(const float4*)(qp + kc * 32);
            const float4 f1 = *(const float4*)(qp + kc * 32 + 4);
            qf[qs][kc][0]=(__bf16)(f0.x*SCALE_LOG2); qf[qs][kc][1]=(__bf16)(f0.y*SCALE_LOG2);
            qf[qs][kc][2]=(__bf16)(f0.z*SCALE_LOG2); qf[qs][kc][3]=(__bf16)(f0.w*SCALE_LOG2);
            qf[qs][kc][4]=(__bf16)(f1.x*SCALE_LOG2); qf[qs][kc][5]=(__bf16)(f1.y*SCALE_LOG2);
            qf[qs][kc][6]=(__bf16)(f1.z*SCALE_LOG2); qf[qs][kc][7]=(__bf16)(f1.w*SCALE_LOG2);
        }
    }

    f32x4 o[2][4];
#pragma unroll
    for (int qs = 0; qs < 2; ++qs)
#pragma unroll
        for (int mt = 0; mt < 4; ++mt) o[qs][mt] = (f32x4){0.f, 0.f, 0.f, 0.f};
    float lsum[2] = {0.f, 0.f};

    // staging geometry: thread -> row kr (0..63), 64B half h
    const int kr = tid >> 1, h = tid & 1;
    const int kwb = kr * 128, ke = kr & 7, ve = kr & 15;
    const __bf16* kbase = kb + (size_t)bh * T_SEQ * D_HEAD;
    const __bf16* vbase = vt + (size_t)bh * D_HEAD * T_SEQ;
    const unsigned long long* mrow0 = mb + (size_t)(qw + ln) * 32;
    const unsigned long long* mrow1 = mb + (size_t)(qw + 16 + ln) * 32;

    char* KlB = (char*)Kl;
    char* VlB = (char*)Vl;

    bf16x8 kn[4], vn[4];   // prefetch registers (tile kt+1)

    // prologue: tile 0
    {
        const __bf16* kp = kbase + (size_t)kr * D_HEAD + h * 32;
        kn[0]=*(const bf16x8*)kp;      kn[1]=*(const bf16x8*)(kp+8);
        kn[2]=*(const bf16x8*)(kp+16); kn[3]=*(const bf16x8*)(kp+24);
        const __bf16* vp = vbase + (size_t)kr * T_SEQ + h * 32;
        vn[0]=*(const bf16x8*)vp;      vn[1]=*(const bf16x8*)(vp+8);
        vn[2]=*(const bf16x8*)(vp+16); vn[3]=*(const bf16x8*)(vp+24);
    }
    unsigned long long mw0 = mrow0[0], mw1 = mrow1[0];
    {
        char* KB = KlB; char* VB = VlB;
#pragma unroll
        for (int i = 0; i < 4; ++i)
            *(bf16x8*)(KB + kwb + (((4*h + i) ^ ke) << 4)) = kn[i];
#pragma unroll
        for (int i = 0; i < 4; ++i) {
            const bf16x4 lo = __builtin_shufflevector(vn[i], vn[i], 0, 1, 2, 3);
            const bf16x4 hi = __builtin_shufflevector(vn[i], vn[i], 4, 5, 6, 7);
            *(bf16x4*)(VB + kwb + (((8*h + 2*i)     ^ ve) << 3)) = lo;
            *(bf16x4*)(VB + kwb + (((8*h + 2*i + 1) ^ ve) << 3)) = hi;
        }
    }
    __syncthreads();

    const int rbK = ln * 128 + ((g ^ (ln & 7)) << 4);   // kc=0 chunk; kc=1 = ^64

    for (int kt = 0; kt < T_SEQ / 64; ++kt) {
        const int b = kt & 1;
        unsigned long long mn0 = 0, mn1 = 0;
        if (kt < 31) {
            const __bf16* kp = kbase + (size_t)((kt + 1) * 64 + kr) * D_HEAD + h * 32;
            kn[0]=*(const bf16x8*)kp;      kn[1]=*(const bf16x8*)(kp+8);
            kn[2]=*(const bf16x8*)(kp+16); kn[3]=*(const bf16x8*)(kp+24);
            const __bf16* vp = vbase + (size_t)kr * T_SEQ + (kt + 1) * 64 + h * 32;
            vn[0]=*(const bf16x8*)vp;      vn[1]=*(const bf16x8*)(vp+8);
            vn[2]=*(const bf16x8*)(vp+16); vn[3]=*(const bf16x8*)(vp+24);
            mn0 = mrow0[kt + 1]; mn1 = mrow1[kt + 1];
        }

        const char* KB = KlB + b * 8192;
        const char* VB = VlB + b * 8192;

        const unsigned long long s0 = mw0 >> (g * 4), s1 = mw1 >> (g * 4);
        const unsigned int mlo[2] = {(unsigned)s0, (unsigned)s1};
        const unsigned int mhi[2] = {(unsigned)(s0 >> 32), (unsigned)(s1 >> 32)};

        // ---- S^T = K.Q^T, exp2 + mask -> P fragments (registers, A-layout of mfma16)
        bf16x4 pa[2][4];
#pragma unroll
        for (int nt = 0; nt < 4; ++nt) {
            const bf16x8 a0 = *(const bf16x8*)(KB + nt * 2048 + rbK);
            const bf16x8 a1 = *(const bf16x8*)(KB + nt * 2048 + (rbK ^ 64));
#pragma unroll
            for (int qs = 0; qs < 2; ++qs) {
                f32x4 c = (f32x4){0.f, 0.f, 0.f, 0.f};
                c = __builtin_amdgcn_mfma_f32_16x16x32_bf16(a0, qf[qs][0], c, 0, 0, 0);
                c = __builtin_amdgcn_mfma_f32_16x16x32_bf16(a1, qf[qs][1], c, 0, 0, 0);
                const unsigned int bits = (nt < 2) ? mlo[qs] : mhi[qs];
                float p[4];
#pragma unroll
                for (int r = 0; r < 4; ++r) {
                    const float e = exp2f(c[r]);
                    p[r] = (bits & (1u << ((nt & 1) * 16 + r))) ? 0.f : e;
                }
                lsum[qs] += (p[0] + p[1]) + (p[2] + p[3]);
                pa[qs][nt] = (bf16x4){ (__bf16)p[0], (__bf16)p[1], (__bf16)p[2], (__bf16)p[3] };
            }
        }

        // ---- PV: O[q][d] += P * V, B-frag = V[key=nt*16+g*4..][d=mt*16+ln] from V^T LDS
#pragma unroll
        for (int mt = 0; mt < 4; ++mt) {
            bf16x4 vf[4];
#pragma unroll
            for (int nt = 0; nt < 4; ++nt)
                vf[nt] = *(const bf16x4*)(VB + (mt * 16 + ln) * 128 + (((nt * 4 + g) ^ (ln & 15)) << 3));
#pragma unroll
            for (int qs = 0; qs < 2; ++qs)
#pragma unroll
                for (int nt = 0; nt < 4; ++nt)
                    o[qs][mt] = mfma16(pa[qs][nt], vf[nt], o[qs][mt]);
        }

        // ---- stage tile kt+1 into the other buffer, single barrier per iter
        if (kt < 31) {
            char* KB1 = KlB + (b ^ 1) * 8192;
            char* VB1 = VlB + (b ^ 1) * 8192;
#pragma unroll
            for (int i = 0; i < 4; ++i)
                *(bf16x8*)(KB1 + kwb + (((4*h + i) ^ ke) << 4)) = kn[i];
#pragma unroll
            for (int i = 0; i < 4; ++i) {
                const bf16x4 lo = __builtin_shufflevector(vn[i], vn[i], 0, 1, 2, 3);
                const bf16x4 hi = __builtin_shufflevector(vn[i], vn[i], 4, 5, 6, 7);
                *(bf16x4*)(VB1 + kwb + (((8*h + 2*i)     ^ ve) << 3)) = lo;
                *(bf16x4*)(VB1 + kwb + (((8*h + 2*i + 1) ^ ve) << 3)) = hi;
            }
        }
        __syncthreads();
        mw0 = mn0; mw1 = mn1;
    }

    // ---- epilogue: 1/l per q-row via cross-lane reduce + tiny LDS transpose
#pragma unroll
    for (int qs = 0; qs < 2; ++qs) {
        float l = lsum[qs];
        l += __shfl_xor(l, 16, 64);
        l += __shfl_xor(l, 32, 64);
        const float inv = (l > 0.f) ? (1.f / l) : 0.f;
        if (g == 0) ls[wave][qs * 16 + ln] = inv;   // wave-private; DS in-order, no barrier
    }
#pragma unroll
    for (int qs = 0; qs < 2; ++qs) {
#pragma unroll
        for (int r = 0; r < 4; ++r) {
            const float iv = ls[wave][qs * 16 + g * 4 + r];
            float* op = out + ((size_t)bh * T_SEQ + qw + qs * 16 + g * 4 + r) * D_HEAD + ln;
#pragma unroll
            for (int mt = 0; mt < 4; ++mt)
                op[mt * 16] = o[qs][mt][r] * iv;
        }
    }
}

extern "C" void kernel_launch(void* const* d_in, const int* in_sizes, int n_in,
                              void* d_out, int out_size, void* d_ws, size_t ws_size,
                              hipStream_t stream) {
    const float* q    = (const float*)d_in[0];
    const float* k    = (const float*)d_in[1];
    const float* v    = (const float*)d_in[2];
    const int*   mask = (const int*)d_in[3];
    float*       out  = (float*)d_out;

    __bf16* kbf = (__bf16*)((char*)d_ws + WS_KBF);
    __bf16* vtb = (__bf16*)((char*)d_ws + WS_VTB);
    unsigned long long* mbw = (unsigned long long*)((char*)d_ws + WS_MB);

    prep_kv<<<dim3(T_SEQ / 64, BH_N), 256, 0, stream>>>(k, v, kbf, vtb);
    mpack<<<(T_SEQ * T_SEQ) / 256, 256, 0, stream>>>(mask, mbw);
    attn5<<<dim3(T_SEQ / 64, BH_N), 128, 0, stream>>>(q, kbf, vtb, mbw, out);
}

// Round 6
// 177.547 us; speedup vs baseline: 1.5628x; 1.0461x over previous
//
#include <hip/hip_runtime.h>
#include <hip/hip_bf16.h>

typedef __bf16 bf16x8 __attribute__((ext_vector_type(8)));
typedef __bf16 bf16x4 __attribute__((ext_vector_type(4)));
typedef float  f32x4  __attribute__((ext_vector_type(4)));
typedef short  s16x4  __attribute__((ext_vector_type(4)));

#define T_SEQ 2048
#define D_HEAD 64
#define BH_N 32
#define SCALE_LOG2 0.18033688011112042f   // 0.125 * log2(e)

// workspace layout (bytes); kbf 8MB, vtb 8MB, mask bitwords 512KB
#define WS_KBF ((size_t)0)
#define WS_VTB ((size_t)8u<<20)
#define WS_MB  ((size_t)16u<<20)

// D = A*B + C, 16x16x16 bf16 (K=16). A: [m=lane&15][k=(lane>>4)*4+r]
static __device__ inline f32x4 mfma16(bf16x4 a, bf16x4 b, f32x4 c) {
#if __has_builtin(__builtin_amdgcn_mfma_f32_16x16x16_bf16)
    return __builtin_amdgcn_mfma_f32_16x16x16_bf16(a, b, c, 0, 0, 0);
#else
    s16x4 ai = __builtin_bit_cast(s16x4, a);
    s16x4 bi = __builtin_bit_cast(s16x4, b);
    return __builtin_amdgcn_mfma_f32_16x16x16bf16_1k(ai, bi, c, 0, 0, 0);
#endif
}

// ---------------- fused prepass: K -> bf16 [bh][t][d], V -> bf16 transposed [bh][d][t] ----------------

__global__ __launch_bounds__(256) void prep_kv(const float* __restrict__ k,
                                               const float* __restrict__ v,
                                               __bf16* __restrict__ kb,
                                               __bf16* __restrict__ vt) {
    __shared__ __bf16 t[64][72];
    const int bh = blockIdx.y, tt = blockIdx.x, tid = threadIdx.x;

    // ---- K convert: row tid>>2, 16 floats at (tid&3)*16
    {
        const size_t base = ((size_t)bh * T_SEQ + tt * 64 + (tid >> 2)) * D_HEAD + (tid & 3) * 16;
        const float4 a0 = *(const float4*)(k + base);
        const float4 a1 = *(const float4*)(k + base + 4);
        const float4 a2 = *(const float4*)(k + base + 8);
        const float4 a3 = *(const float4*)(k + base + 12);
        bf16x8 w0, w1;
        w0[0]=(__bf16)a0.x; w0[1]=(__bf16)a0.y; w0[2]=(__bf16)a0.z; w0[3]=(__bf16)a0.w;
        w0[4]=(__bf16)a1.x; w0[5]=(__bf16)a1.y; w0[6]=(__bf16)a1.z; w0[7]=(__bf16)a1.w;
        w1[0]=(__bf16)a2.x; w1[1]=(__bf16)a2.y; w1[2]=(__bf16)a2.z; w1[3]=(__bf16)a2.w;
        w1[4]=(__bf16)a3.x; w1[5]=(__bf16)a3.y; w1[6]=(__bf16)a3.z; w1[7]=(__bf16)a3.w;
        *(bf16x8*)(kb + base)     = w0;
        *(bf16x8*)(kb + base + 8) = w1;
    }
    // ---- V transpose via LDS
    {
        const int tr = tid >> 4, c4 = (tid & 15) * 4;
        const float* src = v + ((size_t)bh * T_SEQ + tt * 64) * D_HEAD;
#pragma unroll
        for (int p = 0; p < 4; ++p) {
            const int row = p * 16 + tr;
            const float4 f = *(const float4*)(src + row * D_HEAD + c4);
            t[c4+0][row] = (__bf16)f.x; t[c4+1][row] = (__bf16)f.y;
            t[c4+2][row] = (__bf16)f.z; t[c4+3][row] = (__bf16)f.w;
        }
        __syncthreads();
        const int d = tid >> 2, seg = tid & 3;
        const bf16x8 a = *(bf16x8*)&t[d][seg * 16];
        const bf16x8 b = *(bf16x8*)&t[d][seg * 16 + 8];
        __bf16* dst = vt + ((size_t)bh * D_HEAD + d) * T_SEQ + tt * 64 + seg * 16;
        *(bf16x8*)dst = a; *(bf16x8*)(dst + 8) = b;
    }
}

__global__ void mpack(const int* __restrict__ m, unsigned long long* __restrict__ mb) {
    const int i = blockIdx.x * 256 + threadIdx.x;
    const unsigned long long b = __ballot(m[i] != 0);
    if ((threadIdx.x & 63) == 0) mb[i >> 6] = b;
}

// ---------------- main kernel ----------------
// 256 threads = 4 waves x 16 q-rows (4096 waves total -> 50% occupancy cap).
// S^T = K.Q^T via 16x16x32 MFMA (A=K from LDS, B=Q regs). P stays in REGISTERS
// (S^T C-layout == A-layout of 16x16x16 MFMA). Row-sum l via MFMA-with-ones.
// K/V double-buffered in LDS with register prefetch, one barrier/iter.
// No running max (log2-domain scores bounded; fp32 exp2 safe). Mask via u64 bitwords.

__global__ __launch_bounds__(256, 4) void attn6(
    const float* __restrict__ q, const __bf16* __restrict__ kb,
    const __bf16* __restrict__ vt, const unsigned long long* __restrict__ mb,
    float* __restrict__ out)
{
    const int qt = blockIdx.x;   // 0..31
    const int bh = blockIdx.y;   // 0..31
    const int tid = threadIdx.x, wave = tid >> 6, lane = tid & 63;
    const int g = lane >> 4, ln = lane & 15;

    __shared__ __align__(16) __bf16 Kl[2][64 * 64];   // [key][d], 16B-XOR swizzle, stride 128B
    __shared__ __align__(16) __bf16 Vl[2][64 * 64];   // [d][key], 8B-XOR swizzle, stride 128B

    const int qw = qt * 64 + wave * 16;

    // ---- Q B-frag (log2-scaled): lane n=ln holds Q[q=qw+ln][d=kc*32+g*8+j]
    bf16x8 qf[2];
    {
        const float* qp = q + ((size_t)bh * T_SEQ + qw + ln) * D_HEAD + g * 8;
#pragma unroll
        for (int kc = 0; kc < 2; ++kc) {
            const float4 f0 = *(const float4*)(qp + kc * 32);
            const float4 f1 = *(const float4*)(qp + kc * 32 + 4);
            qf[kc][0]=(__bf16)(f0.x*SCALE_LOG2); qf[kc][1]=(__bf16)(f0.y*SCALE_LOG2);
            qf[kc][2]=(__bf16)(f0.z*SCALE_LOG2); qf[kc][3]=(__bf16)(f0.w*SCALE_LOG2);
            qf[kc][4]=(__bf16)(f1.x*SCALE_LOG2); qf[kc][5]=(__bf16)(f1.y*SCALE_LOG2);
            qf[kc][6]=(__bf16)(f1.z*SCALE_LOG2); qf[kc][7]=(__bf16)(f1.w*SCALE_LOG2);
        }
    }

    f32x4 o[4];
#pragma unroll
    for (int mt = 0; mt < 4; ++mt) o[mt] = (f32x4){0.f, 0.f, 0.f, 0.f};
    f32x4 osum = (f32x4){0.f, 0.f, 0.f, 0.f};   // row-sums of P via MFMA-with-ones
    const bf16x4 ones = { (__bf16)1.0f, (__bf16)1.0f, (__bf16)1.0f, (__bf16)1.0f };

    // staging geometry: 256 threads; row kr = tid>>2 (0..63), quarter qd = tid&3 (32B)
    const int kr = tid >> 2, qd = tid & 3;
    const int kwb = kr * 128, ke = kr & 7, ve = kr & 15;
    const __bf16* kbase = kb + (size_t)bh * T_SEQ * D_HEAD;
    const __bf16* vbase = vt + (size_t)bh * D_HEAD * T_SEQ;
    const unsigned long long* mrow = mb + (size_t)(qw + ln) * 32;

    char* KlB = (char*)Kl;
    char* VlB = (char*)Vl;

    bf16x8 kn[2], vn[2];   // prefetch registers (tile kt+1)

    // prologue: tile 0
    {
        const __bf16* kp = kbase + (size_t)kr * D_HEAD + qd * 16;
        kn[0] = *(const bf16x8*)kp; kn[1] = *(const bf16x8*)(kp + 8);
        const __bf16* vp = vbase + (size_t)kr * T_SEQ + qd * 16;
        vn[0] = *(const bf16x8*)vp; vn[1] = *(const bf16x8*)(vp + 8);
    }
    unsigned long long mw = mrow[0];
    {
#pragma unroll
        for (int i = 0; i < 2; ++i)
            *(bf16x8*)(KlB + kwb + (((2*qd + i) ^ ke) << 4)) = kn[i];
#pragma unroll
        for (int i = 0; i < 2; ++i) {
            const bf16x4 lo = __builtin_shufflevector(vn[i], vn[i], 0, 1, 2, 3);
            const bf16x4 hi = __builtin_shufflevector(vn[i], vn[i], 4, 5, 6, 7);
            *(bf16x4*)(VlB + kwb + (((4*qd + 2*i)     ^ ve) << 3)) = lo;
            *(bf16x4*)(VlB + kwb + (((4*qd + 2*i + 1) ^ ve) << 3)) = hi;
        }
    }
    __syncthreads();

    const int rbK = ln * 128 + ((g ^ (ln & 7)) << 4);   // kc=0 chunk; kc=1 = ^64

    for (int kt = 0; kt < T_SEQ / 64; ++kt) {
        const int b = kt & 1;
        unsigned long long mn = 0;
        if (kt < 31) {
            const __bf16* kp = kbase + (size_t)((kt + 1) * 64 + kr) * D_HEAD + qd * 16;
            kn[0] = *(const bf16x8*)kp; kn[1] = *(const bf16x8*)(kp + 8);
            const __bf16* vp = vbase + (size_t)kr * T_SEQ + (kt + 1) * 64 + qd * 16;
            vn[0] = *(const bf16x8*)vp; vn[1] = *(const bf16x8*)(vp + 8);
            mn = mrow[kt + 1];
        }

        const char* KB = KlB + b * 8192;
        const char* VB = VlB + b * 8192;

        const unsigned long long s = mw >> (g * 4);
        const unsigned int mlo = (unsigned)s, mhi = (unsigned)(s >> 32);

        // ---- S^T = K.Q^T, exp2 + mask -> P fragments (registers, A-layout of mfma16)
        bf16x4 pa[4];
#pragma unroll
        for (int nt = 0; nt < 4; ++nt) {
            const bf16x8 a0 = *(const bf16x8*)(KB + nt * 2048 + rbK);
            const bf16x8 a1 = *(const bf16x8*)(KB + nt * 2048 + (rbK ^ 64));
            f32x4 c = (f32x4){0.f, 0.f, 0.f, 0.f};
            c = __builtin_amdgcn_mfma_f32_16x16x32_bf16(a0, qf[0], c, 0, 0, 0);
            c = __builtin_amdgcn_mfma_f32_16x16x32_bf16(a1, qf[1], c, 0, 0, 0);
            const unsigned int bits = (nt < 2) ? mlo : mhi;
            float p[4];
#pragma unroll
            for (int r = 0; r < 4; ++r) {
                const float e = exp2f(c[r]);
                p[r] = (bits & (1u << ((nt & 1) * 16 + r))) ? 0.f : e;
            }
            pa[nt] = (bf16x4){ (__bf16)p[0], (__bf16)p[1], (__bf16)p[2], (__bf16)p[3] };
        }

        // ---- row-sums on the MFMA pipe (B = ones): osum[r] += sum_k P[q=g*4+r][k]
#pragma unroll
        for (int nt = 0; nt < 4; ++nt)
            osum = mfma16(pa[nt], ones, osum);

        // ---- PV: O[q][d] += P * V, B-frag = V[key=nt*16+g*4..][d=mt*16+ln] from V^T LDS
#pragma unroll
        for (int mt = 0; mt < 4; ++mt) {
            bf16x4 vf[4];
#pragma unroll
            for (int nt = 0; nt < 4; ++nt)
                vf[nt] = *(const bf16x4*)(VB + (mt * 16 + ln) * 128 + (((nt * 4 + g) ^ (ln & 15)) << 3));
#pragma unroll
            for (int nt = 0; nt < 4; ++nt)
                o[mt] = mfma16(pa[nt], vf[nt], o[mt]);
        }

        // ---- stage tile kt+1 into the other buffer, single barrier per iter
        if (kt < 31) {
            char* KB1 = KlB + (b ^ 1) * 8192;
            char* VB1 = VlB + (b ^ 1) * 8192;
#pragma unroll
            for (int i = 0; i < 2; ++i)
                *(bf16x8*)(KB1 + kwb + (((2*qd + i) ^ ke) << 4)) = kn[i];
#pragma unroll
            for (int i = 0; i < 2; ++i) {
                const bf16x4 lo = __builtin_shufflevector(vn[i], vn[i], 0, 1, 2, 3);
                const bf16x4 hi = __builtin_shufflevector(vn[i], vn[i], 4, 5, 6, 7);
                *(bf16x4*)(VB1 + kwb + (((4*qd + 2*i)     ^ ve) << 3)) = lo;
                *(bf16x4*)(VB1 + kwb + (((4*qd + 2*i + 1) ^ ve) << 3)) = hi;
            }
        }
        __syncthreads();
        mw = mn;
    }

    // ---- epilogue: inv = 1/l directly from osum (replicated over ln); O rows q=g*4+r
#pragma unroll
    for (int r = 0; r < 4; ++r) {
        const float l = osum[r];
        const float inv = (l > 0.f) ? (1.f / l) : 0.f;
        float* op = out + ((size_t)bh * T_SEQ + qw + g * 4 + r) * D_HEAD + ln;
#pragma unroll
        for (int mt = 0; mt < 4; ++mt)
            op[mt * 16] = o[mt][r] * inv;
    }
}

extern "C" void kernel_launch(void* const* d_in, const int* in_sizes, int n_in,
                              void* d_out, int out_size, void* d_ws, size_t ws_size,
                              hipStream_t stream) {
    const float* q    = (const float*)d_in[0];
    const float* k    = (const float*)d_in[1];
    const float* v    = (const float*)d_in[2];
    const int*   mask = (const int*)d_in[3];
    float*       out  = (float*)d_out;

    __bf16* kbf = (__bf16*)((char*)d_ws + WS_KBF);
    __bf16* vtb = (__bf16*)((char*)d_ws + WS_VTB);
    unsigned long long* mbw = (unsigned long long*)((char*)d_ws + WS_MB);

    prep_kv<<<dim3(T_SEQ / 64, BH_N), 256, 0, stream>>>(k, v, kbf, vtb);
    mpack<<<(T_SEQ * T_SEQ) / 256, 256, 0, stream>>>(mask, mbw);
    attn6<<<dim3(T_SEQ / 64, BH_N), 256, 0, stream>>>(q, kbf, vtb, mbw, out);
}

// Round 7
// 166.778 us; speedup vs baseline: 1.6637x; 1.0646x over previous
//
#include <hip/hip_runtime.h>
#include <hip/hip_bf16.h>

typedef __bf16 bf16x8 __attribute__((ext_vector_type(8)));
typedef __bf16 bf16x4 __attribute__((ext_vector_type(4)));
typedef float  f32x4  __attribute__((ext_vector_type(4)));
typedef short  s16x4  __attribute__((ext_vector_type(4)));

#define T_SEQ 2048
#define D_HEAD 64
#define BH_N 32
#define SCALE_LOG2 0.18033688011112042f   // 0.125 * log2(e)

#define WS_KBF ((size_t)0)
#define WS_VTB ((size_t)8u<<20)
#define WS_MB  ((size_t)16u<<20)

static __device__ inline f32x4 mfma16(bf16x4 a, bf16x4 b, f32x4 c) {
#if __has_builtin(__builtin_amdgcn_mfma_f32_16x16x16_bf16)
    return __builtin_amdgcn_mfma_f32_16x16x16_bf16(a, b, c, 0, 0, 0);
#else
    s16x4 ai = __builtin_bit_cast(s16x4, a);
    s16x4 bi = __builtin_bit_cast(s16x4, b);
    return __builtin_amdgcn_mfma_f32_16x16x16bf16_1k(ai, bi, c, 0, 0, 0);
#endif
}

static __device__ inline float fast_exp2(float x) {
#if __has_builtin(__builtin_amdgcn_exp2f)
    return __builtin_amdgcn_exp2f(x);   // raw v_exp_f32; inputs bounded, no fixup needed
#else
    return exp2f(x);
#endif
}

// ---------------- fused prepass: K -> bf16 [bh][t][d], V -> bf16 transposed [bh][d][t] ----------------

__global__ __launch_bounds__(256) void prep_kv(const float* __restrict__ k,
                                               const float* __restrict__ v,
                                               __bf16* __restrict__ kb,
                                               __bf16* __restrict__ vt) {
    __shared__ __bf16 t[64][72];
    const int bh = blockIdx.y, tt = blockIdx.x, tid = threadIdx.x;
    {
        const size_t base = ((size_t)bh * T_SEQ + tt * 64 + (tid >> 2)) * D_HEAD + (tid & 3) * 16;
        const float4 a0 = *(const float4*)(k + base);
        const float4 a1 = *(const float4*)(k + base + 4);
        const float4 a2 = *(const float4*)(k + base + 8);
        const float4 a3 = *(const float4*)(k + base + 12);
        bf16x8 w0, w1;
        w0[0]=(__bf16)a0.x; w0[1]=(__bf16)a0.y; w0[2]=(__bf16)a0.z; w0[3]=(__bf16)a0.w;
        w0[4]=(__bf16)a1.x; w0[5]=(__bf16)a1.y; w0[6]=(__bf16)a1.z; w0[7]=(__bf16)a1.w;
        w1[0]=(__bf16)a2.x; w1[1]=(__bf16)a2.y; w1[2]=(__bf16)a2.z; w1[3]=(__bf16)a2.w;
        w1[4]=(__bf16)a3.x; w1[5]=(__bf16)a3.y; w1[6]=(__bf16)a3.z; w1[7]=(__bf16)a3.w;
        *(bf16x8*)(kb + base)     = w0;
        *(bf16x8*)(kb + base + 8) = w1;
    }
    {
        const int tr = tid >> 4, c4 = (tid & 15) * 4;
        const float* src = v + ((size_t)bh * T_SEQ + tt * 64) * D_HEAD;
#pragma unroll
        for (int p = 0; p < 4; ++p) {
            const int row = p * 16 + tr;
            const float4 f = *(const float4*)(src + row * D_HEAD + c4);
            t[c4+0][row] = (__bf16)f.x; t[c4+1][row] = (__bf16)f.y;
            t[c4+2][row] = (__bf16)f.z; t[c4+3][row] = (__bf16)f.w;
        }
        __syncthreads();
        const int d = tid >> 2, seg = tid & 3;
        const bf16x8 a = *(bf16x8*)&t[d][seg * 16];
        const bf16x8 b = *(bf16x8*)&t[d][seg * 16 + 8];
        __bf16* dst = vt + ((size_t)bh * D_HEAD + d) * T_SEQ + tt * 64 + seg * 16;
        *(bf16x8*)dst = a; *(bf16x8*)(dst + 8) = b;
    }
}

__global__ void mpack(const int* __restrict__ m, unsigned long long* __restrict__ mb) {
    const int i = blockIdx.x * 256 + threadIdx.x;
    const unsigned long long b = __ballot(m[i] != 0);
    if ((threadIdx.x & 63) == 0) mb[i >> 6] = b;
}

// ---------------- main kernel ----------------
// Block = 256 thr = 4 waves over 64 q-rows: wave (qp = w&1 -> which 32 q, kh = w>>1 -> which
// 32-key half of each 64-key tile). Each wave: 32 q x 32 keys per iter -> K/V frag reads
// amortize over 32 q while wave count stays 4096 (16 waves/CU resident).
// S^T = K.Q^T (16x16x32, A=K LDS, B=Q regs); P stays in registers (C-layout == A-layout of
// 16x16x16); row-sum l via MFMA-with-ones; raw v_exp_f32; mask via bfe_i32+and on bitwords.
// V stored in LDS with [g][nt][r] key permutation so PV B-frags are b128 loads.
// kh halves combined once at the end through LDS. Double-buffered staging, 1 barrier/iter.

__global__ __launch_bounds__(256, 4) void attn8(
    const float* __restrict__ q, const __bf16* __restrict__ kb,
    const __bf16* __restrict__ vt, const unsigned long long* __restrict__ mb,
    float* __restrict__ out)
{
    const int qt = blockIdx.x;   // 0..31 (64 q rows per block)
    const int bh = blockIdx.y;   // 0..31
    const int tid = threadIdx.x, wave = tid >> 6, lane = tid & 63;
    const int g = lane >> 4, ln = lane & 15;
    const int qp = wave & 1, kh = wave >> 1;

    __shared__ __align__(16) char smem[33280];
    char* KlB = smem;             // [2][64 rows x 128B]  K tiles (16B-XOR swizzle)
    char* VlB = smem + 16384;     // [2][64 rows x 128B]  V^T tiles, permuted keys
    float* Ep = (float*)smem;     // epilogue: [2][64][64] f32 (32KB, reuses K/V space)
    float* Os = (float*)(smem + 32768);  // [2][64] row sums

    const int qw = qt * 64 + qp * 32;

    // ---- Q B-frags (log2-scaled): qf[qs][kc], lane n=ln holds Q[qw+qs*16+ln][kc*32+g*8+j]
    bf16x8 qf[2][2];
#pragma unroll
    for (int qs = 0; qs < 2; ++qs) {
        const float* qpt = q + ((size_t)bh * T_SEQ + qw + qs * 16 + ln) * D_HEAD + g * 8;
#pragma unroll
        for (int kc = 0; kc < 2; ++kc) {
            const float4 f0 = *(const float4*)(qpt + kc * 32);
            const float4 f1 = *(const float4*)(qpt + kc * 32 + 4);
            qf[qs][kc][0]=(__bf16)(f0.x*SCALE_LOG2); qf[qs][kc][1]=(__bf16)(f0.y*SCALE_LOG2);
            qf[qs][kc][2]=(__bf16)(f0.z*SCALE_LOG2); qf[qs][kc][3]=(__bf16)(f0.w*SCALE_LOG2);
            qf[qs][kc][4]=(__bf16)(f1.x*SCALE_LOG2); qf[qs][kc][5]=(__bf16)(f1.y*SCALE_LOG2);
            qf[qs][kc][6]=(__bf16)(f1.z*SCALE_LOG2); qf[qs][kc][7]=(__bf16)(f1.w*SCALE_LOG2);
        }
    }

    f32x4 o[2][4];
#pragma unroll
    for (int qs = 0; qs < 2; ++qs)
#pragma unroll
        for (int mt = 0; mt < 4; ++mt) o[qs][mt] = (f32x4){0.f, 0.f, 0.f, 0.f};
    f32x4 osum[2] = { (f32x4){0.f,0.f,0.f,0.f}, (f32x4){0.f,0.f,0.f,0.f} };
    const bf16x4 ones = { (__bf16)1.0f, (__bf16)1.0f, (__bf16)1.0f, (__bf16)1.0f };

    // staging geometry: row kr = tid>>2 (0..63), quarter qd = tid&3 (32B each)
    const int kr = tid >> 2, qd = tid & 3;
    const int kwb = kr * 128, ke = kr & 7;
    const __bf16* kbase = kb + (size_t)bh * T_SEQ * D_HEAD;
    const __bf16* vbase = vt + (size_t)bh * D_HEAD * T_SEQ;
    const unsigned long long* mrow0 = mb + (size_t)(qw + ln) * 32;
    const unsigned long long* mrow1 = mb + (size_t)(qw + 16 + ln) * 32;

    bf16x8 kn[2], vn[2];   // prefetch registers

    // prologue: tile 0
    {
        const __bf16* kp = kbase + (size_t)kr * D_HEAD + qd * 16;
        kn[0] = *(const bf16x8*)kp; kn[1] = *(const bf16x8*)(kp + 8);
        const __bf16* vp = vbase + (size_t)kr * T_SEQ + qd * 16;
        vn[0] = *(const bf16x8*)vp; vn[1] = *(const bf16x8*)(vp + 8);
    }
    unsigned long long mw0 = mrow0[0], mw1 = mrow1[0];
    {
        *(bf16x8*)(KlB + kwb + (((2*qd + 0) ^ ke) << 4)) = kn[0];
        *(bf16x8*)(KlB + kwb + (((2*qd + 1) ^ ke) << 4)) = kn[1];
#pragma unroll
        for (int c = 0; c < 2; ++c)
#pragma unroll
            for (int gg = 0; gg < 2; ++gg) {
                const int g2 = c * 2 + gg;
                const int gran = (g2 << 1) | (qd >> 1);
                const bf16x4 part = gg ? __builtin_shufflevector(vn[c], vn[c], 4,5,6,7)
                                       : __builtin_shufflevector(vn[c], vn[c], 0,1,2,3);
                *(bf16x4*)(VlB + kwb + ((gran ^ ke) << 4) + ((qd & 1) << 3)) = part;
            }
    }
    __syncthreads();

    for (int kt = 0; kt < T_SEQ / 64; ++kt) {
        const int b = kt & 1;
        unsigned long long mn0 = 0, mn1 = 0;
        if (kt < 31) {
            const __bf16* kp = kbase + (size_t)((kt + 1) * 64 + kr) * D_HEAD + qd * 16;
            kn[0] = *(const bf16x8*)kp; kn[1] = *(const bf16x8*)(kp + 8);
            const __bf16* vp = vbase + (size_t)kr * T_SEQ + (kt + 1) * 64 + qd * 16;
            vn[0] = *(const bf16x8*)vp; vn[1] = *(const bf16x8*)(vp + 8);
            mn0 = mrow0[kt + 1]; mn1 = mrow1[kt + 1];
        }

        const char* KB = KlB + b * 8192;
        const char* VB = VlB + b * 8192;

        // pre-inverted keep-bit words for this wave's 32-key half, pre-shifted by g*4
        const unsigned nbs0 = (~(unsigned)(mw0 >> (kh << 5))) >> (g * 4);
        const unsigned nbs1 = (~(unsigned)(mw1 >> (kh << 5))) >> (g * 4);

        // ---- S^T = K.Q^T over this wave's two 16-key groups; exp2+mask -> P frags
        bf16x4 pa[2][2];   // [qs][ntl]
#pragma unroll
        for (int ntl = 0; ntl < 2; ++ntl) {
            const int row = (2 * kh + ntl) * 16 + ln;
            const int rb = row * 128 + ((g ^ (ln & 7)) << 4);
            const bf16x8 a0 = *(const bf16x8*)(KB + rb);
            const bf16x8 a1 = *(const bf16x8*)(KB + (rb ^ 64));
#pragma unroll
            for (int qs = 0; qs < 2; ++qs) {
                f32x4 c = (f32x4){0.f, 0.f, 0.f, 0.f};
                c = __builtin_amdgcn_mfma_f32_16x16x32_bf16(a0, qf[qs][0], c, 0, 0, 0);
                c = __builtin_amdgcn_mfma_f32_16x16x32_bf16(a1, qf[qs][1], c, 0, 0, 0);
                const unsigned nbs = qs ? nbs1 : nbs0;
                float p[4];
#pragma unroll
                for (int r = 0; r < 4; ++r) {
                    const float e = fast_exp2(c[r]);
                    // keep-mask: all-ones if bit (ntl*16+r) of nbs set, else 0 (bfe_i32 pattern)
                    const int keep = (int)(nbs << (31 - (ntl * 16 + r))) >> 31;
                    p[r] = __builtin_bit_cast(float, __builtin_bit_cast(unsigned, e) & (unsigned)keep);
                }
                pa[qs][ntl] = (bf16x4){ (__bf16)p[0], (__bf16)p[1], (__bf16)p[2], (__bf16)p[3] };
                osum[qs] = mfma16(pa[qs][ntl], ones, osum[qs]);
            }
        }

        // ---- PV: b128 V-frags (permuted layout) cover both ntl groups at once
#pragma unroll
        for (int mt = 0; mt < 4; ++mt) {
            const int vrow = mt * 16 + ln;
            const bf16x8 vv = *(const bf16x8*)(VB + vrow * 128 + ((((g << 1) | kh) ^ (ln & 7)) << 4));
            const bf16x4 vf0 = __builtin_shufflevector(vv, vv, 0, 1, 2, 3);
            const bf16x4 vf1 = __builtin_shufflevector(vv, vv, 4, 5, 6, 7);
#pragma unroll
            for (int qs = 0; qs < 2; ++qs) {
                o[qs][mt] = mfma16(pa[qs][0], vf0, o[qs][mt]);
                o[qs][mt] = mfma16(pa[qs][1], vf1, o[qs][mt]);
            }
        }

        // ---- stage tile kt+1 into the other buffer, single barrier per iter
        if (kt < 31) {
            char* KB1 = KlB + (b ^ 1) * 8192;
            char* VB1 = VlB + (b ^ 1) * 8192;
            *(bf16x8*)(KB1 + kwb + (((2*qd + 0) ^ ke) << 4)) = kn[0];
            *(bf16x8*)(KB1 + kwb + (((2*qd + 1) ^ ke) << 4)) = kn[1];
#pragma unroll
            for (int c = 0; c < 2; ++c)
#pragma unroll
                for (int gg = 0; gg < 2; ++gg) {
                    const int g2 = c * 2 + gg;
                    const int gran = (g2 << 1) | (qd >> 1);
                    const bf16x4 part = gg ? __builtin_shufflevector(vn[c], vn[c], 4,5,6,7)
                                           : __builtin_shufflevector(vn[c], vn[c], 0,1,2,3);
                    *(bf16x4*)(VB1 + kwb + ((gran ^ ke) << 4) + ((qd & 1) << 3)) = part;
                }
        }
        __syncthreads();
        mw0 = mn0; mw1 = mn1;
    }

    // ---- epilogue: combine kh halves through LDS (K/V buffers are dead now)
#pragma unroll
    for (int qs = 0; qs < 2; ++qs) {
#pragma unroll
        for (int mt = 0; mt < 4; ++mt)
#pragma unroll
            for (int r = 0; r < 4; ++r)
                Ep[(size_t)kh * 4096 + (qp * 32 + qs * 16 + g * 4 + r) * 64 + mt * 16 + ln] = o[qs][mt][r];
        if (ln == 0) {
#pragma unroll
            for (int r = 0; r < 4; ++r)
                Os[kh * 64 + qp * 32 + qs * 16 + g * 4 + r] = osum[qs][r];
        }
    }
    __syncthreads();
    // cooperative, coalesced output: 64 rows x 64 d fp32
#pragma unroll
    for (int p = 0; p < 4; ++p) {
        const int idx = p * 256 + tid;
        const int row = idx >> 4, c4 = (idx & 15) * 4;
        const float l = Os[row] + Os[64 + row];
        const float inv = (l > 0.f) ? (1.f / l) : 0.f;
        const float4 a  = *(const float4*)(Ep + row * 64 + c4);
        const float4 b4 = *(const float4*)(Ep + 4096 + row * 64 + c4);
        const float4 st = { (a.x + b4.x) * inv, (a.y + b4.y) * inv,
                            (a.z + b4.z) * inv, (a.w + b4.w) * inv };
        *(float4*)(out + ((size_t)bh * T_SEQ + qt * 64 + row) * D_HEAD + c4) = st;
    }
}

extern "C" void kernel_launch(void* const* d_in, const int* in_sizes, int n_in,
                              void* d_out, int out_size, void* d_ws, size_t ws_size,
                              hipStream_t stream) {
    const float* q    = (const float*)d_in[0];
    const float* k    = (const float*)d_in[1];
    const float* v    = (const float*)d_in[2];
    const int*   mask = (const int*)d_in[3];
    float*       out  = (float*)d_out;

    __bf16* kbf = (__bf16*)((char*)d_ws + WS_KBF);
    __bf16* vtb = (__bf16*)((char*)d_ws + WS_VTB);
    unsigned long long* mbw = (unsigned long long*)((char*)d_ws + WS_MB);

    prep_kv<<<dim3(T_SEQ / 64, BH_N), 256, 0, stream>>>(k, v, kbf, vtb);
    mpack<<<(T_SEQ * T_SEQ) / 256, 256, 0, stream>>>(mask, mbw);
    attn8<<<dim3(T_SEQ / 64, BH_N), 256, 0, stream>>>(q, kbf, vtb, mbw, out);
}